// Round 7
// baseline (505.595 us; speedup 1.0000x reference)
//
#include <hip/hip_runtime.h>
#include <math.h>
#include <stdint.h>

#define L_DIM 1024
#define C_DIM 128
#define H_DIM 512
#define B_DIM 16
#define LC (L_DIM * C_DIM)      // 131072
#define BLC (B_DIM * LC)        // 2097152

typedef __attribute__((ext_vector_type(8))) short short8;
typedef __attribute__((ext_vector_type(4))) float floatx4;

// ---------------- monotone float/bits -> ordered uint ----------------------
__device__ __forceinline__ unsigned ford(float x) {
    unsigned u = __float_as_uint(x);
    return (u & 0x80000000u) ? ~u : (u | 0x80000000u);
}
__device__ __forceinline__ unsigned fordbits(unsigned u) {
    return (u & 0x80000000u) ? ~u : (u | 0x80000000u);
}

// ---------------- truncation 3-way bf16 split: x = h + m + l + O(2^-24 x) --
__device__ __forceinline__ void split3(float x, unsigned& uh, unsigned& um,
                                       unsigned& ul) {
    uh = __float_as_uint(x);
    const float r1 = x - __uint_as_float(uh & 0xffff0000u);
    um = __float_as_uint(r1);
    const float r2 = r1 - __uint_as_float(um & 0xffff0000u);
    ul = __float_as_uint(r2);
}

__device__ __forceinline__ float gelu_fast(float x) {
    const float g = 0.7978845608028654f * (x + 0.044715f * x * x * x);
    const float e = __expf(2.0f * g);
    const float t = 1.0f - 2.0f / (e + 1.0f);
    return 0.5f * x * (1.0f + t);
}

// ---------------- W pre-split into MFMA B-frag layout (h/m/l bf16) ---------
__global__ __launch_bounds__(256) void wsplit_kernel(
    const float* __restrict__ W1, const float* __restrict__ W2,
    unsigned short* __restrict__ W1h, unsigned short* __restrict__ W1m,
    unsigned short* __restrict__ W1l, unsigned short* __restrict__ W2h,
    unsigned short* __restrict__ W2m, unsigned short* __restrict__ W2l) {
    const int t = blockIdx.x * 256 + threadIdx.x;  // < 131072
    unsigned uh, um, ul;
    if (t < 65536) {
        const int j = t & 7, lane = (t >> 3) & 63, nt = (t >> 9) & 31,
                  kt = (t >> 14) & 3;
        const int k = kt * 32 + (lane >> 4) * 8 + j;
        const int n = nt * 16 + (lane & 15);
        split3(W1[k * 512 + n], uh, um, ul);
        W1h[t] = (unsigned short)(uh >> 16);
        W1m[t] = (unsigned short)(um >> 16);
        W1l[t] = (unsigned short)(ul >> 16);
    } else {
        const int t2 = t - 65536;
        const int j = t2 & 7, lane = (t2 >> 3) & 63, nt = (t2 >> 9) & 7,
                  kt = (t2 >> 12) & 15;
        const int k = kt * 32 + (lane >> 4) * 8 + j;
        const int n = nt * 16 + (lane & 15);
        split3(W2[k * 128 + n], uh, um, ul);
        W2h[t2] = (unsigned short)(uh >> 16);
        W2m[t2] = (unsigned short)(um >> 16);
        W2l[t2] = (unsigned short)(ul >> 16);
    }
}

// 6-term bf16x3 MFMA accumulate (small terms first); error ~2^-24
#define MFMA6(AH, AM, AL, BH, BM, BL, ACC)                                    \
    ACC = __builtin_amdgcn_mfma_f32_16x16x32_bf16(AL, BH, ACC, 0, 0, 0);      \
    ACC = __builtin_amdgcn_mfma_f32_16x16x32_bf16(AM, BM, ACC, 0, 0, 0);      \
    ACC = __builtin_amdgcn_mfma_f32_16x16x32_bf16(AH, BL, ACC, 0, 0, 0);      \
    ACC = __builtin_amdgcn_mfma_f32_16x16x32_bf16(AM, BH, ACC, 0, 0, 0);      \
    ACC = __builtin_amdgcn_mfma_f32_16x16x32_bf16(AH, BM, ACC, 0, 0, 0);      \
    ACC = __builtin_amdgcn_mfma_f32_16x16x32_bf16(AH, BH, ACC, 0, 0, 0);

// per-element DPM update (identical math to R6 update_kernel)
__device__ __forceinline__ float upd_elem(
    float zi, float yi, float mi, float ei, int l, int c,
    const float* __restrict__ ent, const float* __restrict__ p1,
    const float* __restrict__ p2, const float* __restrict__ p3,
    unsigned t0, unsigned t1, unsigned t2, unsigned t3, float var,
    float base_a, float base_b, float h_lam) {
    float ent_v = 0.f;
    bool sel = false;
    const float v0 = ent[l * 128 + c];
    if (ford(v0) >= t0) { ent_v = v0; sel = true; }
    else {
        const float v1 = p1[((l >> 1) << 6) + (c >> 1)];
        if (ford(v1) >= t1) { ent_v = v1; sel = true; }
        else {
            const float v2 = p2[((l >> 2) << 5) + (c >> 2)];
            if (ford(v2) >= t2) { ent_v = v2; sel = true; }
            else {
                const float v3 = p3[((l >> 3) << 4) + (c >> 3)];
                if (ford(v3) >= t3) { ent_v = v3; sel = true; }
            }
        }
    }
    if (!sel) return zi;
    float corr;
    if (ent_v > 0.5f) corr = 1.0f + h_lam + h_lam * h_lam * (1.0f / 3.0f);
    else if (ent_v > 0.1f) corr = 1.0f + 0.5f * h_lam;
    else corr = 1.0f;
    const float gs = 2.0f * ent_v / (ent_v + 1.0f);
    const float oe = (zi - yi) * mi;
    const float guid = -oe / (var + 1e-8f);
    return base_a * zi - base_b * (corr * ei) + gs * guid;
}

// ---------------- fused MLP (+ previous step's DPM update when UPD) --------
// Block: 512 thr (8 waves), M=32 rows (16 b x 2 l), grid 512.
// LDS holds z and h A-fragments in MFMA fragment order, separate h/m/l
// arrays -> every A-frag read is one lane-contiguous ds_read_b128 (conflict-
// free, zero unpack bitops; R6's packed row-major layout cost 2.4M bank-
// conflict cycles + heavy VALU unpack).
template <int UPD>
__global__ __launch_bounds__(512, 2) void mlp_kernel(
    float* __restrict__ z, const float* __restrict__ y,
    const float* __restrict__ mk,
    const unsigned short* __restrict__ W1h, const unsigned short* __restrict__ W1m,
    const unsigned short* __restrict__ W1l, const unsigned short* __restrict__ W2h,
    const unsigned short* __restrict__ W2m, const unsigned short* __restrict__ W2l,
    const float* __restrict__ b1, const float* __restrict__ tw,
    const float* __restrict__ b2, float t_feat,
    float* __restrict__ eps_buf, float* __restrict__ ent,
    const float* __restrict__ p1, const float* __restrict__ p2,
    const float* __restrict__ p3, const unsigned* __restrict__ gpref,
    const float* __restrict__ accumPrev, float* __restrict__ accum,
    float base_a, float base_b, float h_lam) {
    __shared__ unsigned short zA[3][4096];  // z frags: ((kt*2+il)*64+lane)*8+j
    __shared__ unsigned short hA[3][4096];  // h frags: ((ktl*2+il)*64+lane)*8+j
    __shared__ float red1[8], red2[8];
    const int tid = threadIdx.x;
    const int w = tid >> 6, lane = tid & 63;
    const int quad = lane >> 4, m16 = lane & 15;
    const int l0 = blockIdx.x * 2;

    float var = 0.f;
    unsigned t0 = 0, t1 = 0, t2 = 0, t3 = 0;
    if (UPD) {
        const float mean = accumPrev[0] * (1.0f / (float)BLC);
        var = accumPrev[1] * (1.0f / (float)BLC) - mean * mean;
        t0 = gpref[0]; t1 = gpref[1]; t2 = gpref[2]; t3 = gpref[3];
    }

    // ---- phase 1: (update) + stats + stage split z into fragment-order LDS
    float s1 = 0.f, s2 = 0.f;
#pragma unroll
    for (int e = 0; e < 2; ++e) {
        const int f = tid * 8 + e * 4;  // 0..4095
        const int r_ = f >> 7, cb = f & 127;
        const int b = r_ & 15, il = r_ >> 4, l = l0 + il;
        const size_t g = ((size_t)b * 1024 + l) * 128 + cb;
        float4 zv = *(const float4*)(z + g);
        const float4 yv = *(const float4*)(y + g);
        const float4 mv = *(const float4*)(mk + g);
        if (UPD) {
            const float4 ev = *(const float4*)(eps_buf + g);
            zv.x = upd_elem(zv.x, yv.x, mv.x, ev.x, l, cb + 0, ent, p1, p2, p3,
                            t0, t1, t2, t3, var, base_a, base_b, h_lam);
            zv.y = upd_elem(zv.y, yv.y, mv.y, ev.y, l, cb + 1, ent, p1, p2, p3,
                            t0, t1, t2, t3, var, base_a, base_b, h_lam);
            zv.z = upd_elem(zv.z, yv.z, mv.z, ev.z, l, cb + 2, ent, p1, p2, p3,
                            t0, t1, t2, t3, var, base_a, base_b, h_lam);
            zv.w = upd_elem(zv.w, yv.w, mv.w, ev.w, l, cb + 3, ent, p1, p2, p3,
                            t0, t1, t2, t3, var, base_a, base_b, h_lam);
            *(float4*)(z + g) = zv;
        }
        float oe;
        oe = (zv.x - yv.x) * mv.x; s1 += oe; s2 += oe * oe;
        oe = (zv.y - yv.y) * mv.y; s1 += oe; s2 += oe * oe;
        oe = (zv.z - yv.z) * mv.z; s1 += oe; s2 += oe * oe;
        oe = (zv.w - yv.w) * mv.w; s1 += oe; s2 += oe * oe;

        // fragment-order staging: one ushort4 (b64) write per component
        const int kt = cb >> 5;
        const int fi = ((kt * 2 + il) * 64 + ((cb >> 3) & 3) * 16 + b) * 8 +
                       (cb & 7);
        const float xs[4] = {zv.x, zv.y, zv.z, zv.w};
        ushort4 vh, vm, vl;
        unsigned uh, um, ul;
        split3(xs[0], uh, um, ul); vh.x = uh >> 16; vm.x = um >> 16; vl.x = ul >> 16;
        split3(xs[1], uh, um, ul); vh.y = uh >> 16; vm.y = um >> 16; vl.y = ul >> 16;
        split3(xs[2], uh, um, ul); vh.z = uh >> 16; vm.z = um >> 16; vl.z = ul >> 16;
        split3(xs[3], uh, um, ul); vh.w = uh >> 16; vm.w = um >> 16; vl.w = ul >> 16;
        *(ushort4*)(&zA[0][fi]) = vh;
        *(ushort4*)(&zA[1][fi]) = vm;
        *(ushort4*)(&zA[2][fi]) = vl;
    }
#pragma unroll
    for (int off = 32; off; off >>= 1) {
        s1 += __shfl_down(s1, off);
        s2 += __shfl_down(s2, off);
    }
    if (lane == 0) { red1[w] = s1; red2[w] = s2; }
    __syncthreads();  // staging + red arrays complete
    if (tid == 0) {
        float a1 = 0.f, a2 = 0.f;
#pragma unroll
        for (int i = 0; i < 8; ++i) { a1 += red1[i]; a2 += red2[i]; }
        atomicAdd(&accum[0], a1);
        atomicAdd(&accum[1], a2);
    }

    // ---- GEMM pipeline ----
    floatx4 acc2[2];
    acc2[0] = (floatx4){0.f, 0.f, 0.f, 0.f};
    acc2[1] = (floatx4){0.f, 0.f, 0.f, 0.f};

    for (int hf = 0; hf < 2; ++hf) {
        floatx4 acc1[4];  // [s*2 + il]
#pragma unroll
        for (int i = 0; i < 4; ++i) acc1[i] = (floatx4){0.f, 0.f, 0.f, 0.f};

#pragma unroll
        for (int kt = 0; kt < 4; ++kt) {
            short8 Ah[2], Am[2], Al[2];
#pragma unroll
            for (int il = 0; il < 2; ++il) {
                const int fb = ((kt * 2 + il) * 64 + lane) * 8;
                Ah[il] = *(const short8*)(&zA[0][fb]);
                Am[il] = *(const short8*)(&zA[1][fb]);
                Al[il] = *(const short8*)(&zA[2][fb]);
            }
#pragma unroll
            for (int s = 0; s < 2; ++s) {
                const int nt1 = (hf * 2 + s) * 8 + w;
                const size_t off = ((size_t)(kt * 32 + nt1) * 64 + lane) * 8;
                const short8 bh = *(const short8*)(W1h + off);
                const short8 bm = *(const short8*)(W1m + off);
                const short8 bl = *(const short8*)(W1l + off);
#pragma unroll
                for (int il = 0; il < 2; ++il) {
                    floatx4 a = acc1[s * 2 + il];
                    MFMA6(Ah[il], Am[il], Al[il], bh, bm, bl, a);
                    acc1[s * 2 + il] = a;
                }
            }
        }

#pragma unroll
        for (int s = 0; s < 2; ++s) {
            const int q = hf * 2 + s;
            __syncthreads();  // previous quarter's hA reads done
            {
                const int colg = q * 128 + w * 16 + m16;
                const float bb = b1[colg] + t_feat * tw[colg];
                const int ib = ((w >> 1) * 2) * 64 * 8;  // ktl_w = w>>1, il=0
                const int l2b = (((w & 1) << 1) | (m16 >> 3)) * 16;
                const int jj = m16 & 7;
#pragma unroll
                for (int il = 0; il < 2; ++il) {
#pragma unroll
                    for (int r = 0; r < 4; ++r) {
                        const float x = gelu_fast(acc1[s * 2 + il][r] + bb);
                        unsigned uh, um, ul;
                        split3(x, uh, um, ul);
                        const int idx =
                            ib + il * 512 + (l2b + quad * 4 + r) * 8 + jj;
                        hA[0][idx] = (unsigned short)(uh >> 16);
                        hA[1][idx] = (unsigned short)(um >> 16);
                        hA[2][idx] = (unsigned short)(ul >> 16);
                    }
                }
            }
            __syncthreads();

#pragma unroll
            for (int ktl = 0; ktl < 4; ++ktl) {
                short8 Ah2[2], Am2[2], Al2[2];
#pragma unroll
                for (int il = 0; il < 2; ++il) {
                    const int fb = ((ktl * 2 + il) * 64 + lane) * 8;
                    Ah2[il] = *(const short8*)(&hA[0][fb]);
                    Am2[il] = *(const short8*)(&hA[1][fb]);
                    Al2[il] = *(const short8*)(&hA[2][fb]);
                }
                const int ktg = q * 4 + ktl;
                const size_t off = ((size_t)(ktg * 8 + w) * 64 + lane) * 8;
                const short8 bh = *(const short8*)(W2h + off);
                const short8 bm = *(const short8*)(W2m + off);
                const short8 bl = *(const short8*)(W2l + off);
#pragma unroll
                for (int il = 0; il < 2; ++il) {
                    floatx4 a = acc2[il];
                    MFMA6(Ah2[il], Am2[il], Al2[il], bh, bm, bl, a);
                    acc2[il] = a;
                }
            }
        }
    }

    // ---- epilogue: +b2, write eps, ent = mean_b |eps| ----
    {
        const int col = w * 16 + m16;
        const float bb2 = b2[col];
#pragma unroll
        for (int il = 0; il < 2; ++il) {
            float pa = 0.f;
#pragma unroll
            for (int r = 0; r < 4; ++r) {
                const float e = acc2[il][r] + bb2;
                const int b = quad * 4 + r;
                eps_buf[((size_t)b * 1024 + l0 + il) * 128 + col] = e;
                pa += fabsf(e);
            }
            pa += __shfl_xor(pa, 16);
            pa += __shfl_xor(pa, 32);
            if (quad == 0) ent[(l0 + il) * 128 + col] = pa * (1.0f / 16.0f);
        }
    }
}

// ---------------- device-atomic grid barrier (85 co-resident blocks) -------
__device__ __forceinline__ void grid_barrier(unsigned* ctr, unsigned* rel,
                                             unsigned target) {
    __syncthreads();
    if (threadIdx.x == 0) {
        __threadfence();
        if (atomicAdd(ctr, 1u) + 1u == target) {
            atomicExch(rel, target);
        } else {
            while (atomicAdd(rel, 0u) < target) __builtin_amdgcn_s_sleep(8);
        }
    }
    __syncthreads();
}

// -------- fused select: pools + 4-pass exact radix top-k thresholds --------
// 85 blocks x 256 thr (<=256 CUs -> co-resident, grid barrier safe).
// Cross-block data written within this dispatch uses device atomics only
// (XCD L2 non-coherence, G16). ghist has one pre-zeroed buffer per
// (step, pass); each block keeps its own (prefix,krem) via redundant scan.
__global__ __launch_bounds__(256, 1) void select_kernel(
    const float* __restrict__ ent, float* __restrict__ p1,
    float* __restrict__ p2, float* __restrict__ p3,
    unsigned* __restrict__ ghist, unsigned* __restrict__ ctr,
    unsigned* __restrict__ rel, unsigned* __restrict__ gprefix, int si) {
    const int bid = blockIdx.x, t = threadIdx.x;
    const int gid = bid * 256 + t;
    const unsigned target0 = (unsigned)(si * 5) * 85u;

    // ---- pools, direct from ent (same summation order as R6, ref-proven) --
    for (int i = gid; i < 32768; i += 21760) {  // w=2: 512x64
        const int r = i >> 6, c = i & 63;
        float s = 0.f;
#pragma unroll
        for (int ii = 0; ii < 2; ++ii)
#pragma unroll
            for (int jj = 0; jj < 2; ++jj)
                s += ent[((r * 2 + ii) << 7) + c * 2 + jj];
        atomicExch((unsigned*)&p1[i], __float_as_uint(s * 0.25f));
    }
    for (int i = gid; i < 8192; i += 21760) {  // w=4: 256x32
        const int r = i >> 5, c = i & 31;
        float s = 0.f;
#pragma unroll
        for (int ii = 0; ii < 4; ++ii)
#pragma unroll
            for (int jj = 0; jj < 4; ++jj)
                s += ent[((r * 4 + ii) << 7) + c * 4 + jj];
        atomicExch((unsigned*)&p2[i], __float_as_uint(s * 0.0625f));
    }
    for (int i = gid; i < 2048; i += 21760) {  // w=8: 128x16
        const int r = i >> 4, c = i & 15;
        float s = 0.f;
#pragma unroll
        for (int ii = 0; ii < 8; ++ii)
#pragma unroll
            for (int jj = 0; jj < 8; ++jj)
                s += ent[((r * 8 + ii) << 7) + c * 8 + jj];
        atomicExch((unsigned*)&p3[i], __float_as_uint(s * (1.0f / 64.0f)));
    }
    grid_barrier(ctr, rel, target0 + 85u);

    // ---- radix select ----
    const float* data;
    int scale, base;
    unsigned K;
    if (bid < 64) { scale = 0; data = ent; base = bid * 2048; K = 26214u; }
    else if (bid < 80) { scale = 1; data = p1; base = (bid - 64) * 2048; K = 6553u; }
    else if (bid < 84) { scale = 2; data = p2; base = (bid - 80) * 2048; K = 1638u; }
    else { scale = 3; data = p3; base = 0; K = 409u; }

    __shared__ unsigned hist[4][256];
    __shared__ unsigned sh[256];
    __shared__ unsigned sh_dig, sh_krem;
    const int wv = t >> 6;
    unsigned prefix = 0u, krem = K;

    for (int p = 0; p < 4; ++p) {
        const int shift = 24 - 8 * p;
        const unsigned hmask = p ? (0xFFFFFFFFu << (shift + 8)) : 0u;
#pragma unroll
        for (int i = t; i < 1024; i += 256) ((unsigned*)hist)[i] = 0u;
        __syncthreads();
#pragma unroll
        for (int i = t; i < 2048; i += 256) {
            // atomic load: data may have been written within this dispatch
            const unsigned raw =
                atomicAdd((unsigned*)&data[base + i], 0u);
            const unsigned u = fordbits(raw);
            if ((u & hmask) == (prefix & hmask))
                atomicAdd(&hist[wv][(u >> shift) & 255u], 1u);
        }
        __syncthreads();
        const unsigned c = hist[0][t] + hist[1][t] + hist[2][t] + hist[3][t];
        unsigned* gh = &ghist[((si * 4 + p) * 4 + scale) * 256];
        if (c) atomicAdd(&gh[t], c);
        grid_barrier(ctr, rel, target0 + 85u * (unsigned)(p + 2));
        sh[t] = atomicAdd(&gh[t], 0u);
        __syncthreads();
#pragma unroll
        for (int off = 1; off < 256; off <<= 1) {
            const unsigned v = (t + off < 256) ? sh[t + off] : 0u;
            __syncthreads();
            sh[t] += v;
            __syncthreads();
        }
        const unsigned suf = sh[t];
        const unsigned sufn = (t < 255) ? sh[t + 1] : 0u;
        if (suf >= krem && sufn < krem) {  // unique crossing
            sh_dig = (unsigned)t;
            sh_krem = krem - sufn;
        }
        __syncthreads();
        prefix |= (sh_dig << shift);
        krem = sh_krem;
        __syncthreads();
    }
    if (t == 0 && base == 0) gprefix[scale] = prefix;
}

// ---------------- standalone final update (after step 3's select) ----------
__global__ __launch_bounds__(256) void update_kernel(
    float* __restrict__ z, const float* __restrict__ y,
    const float* __restrict__ mk, const float* __restrict__ eps,
    const float* __restrict__ ent, const float* __restrict__ p1,
    const float* __restrict__ p2, const float* __restrict__ p3,
    const unsigned* __restrict__ thr, const float* __restrict__ accum,
    float base_a, float base_b, float h_lam) {
    const int idx = blockIdx.x * 256 + threadIdx.x;  // < BLC
    const int p = idx & (LC - 1);
    const int l = p >> 7;
    const int c = p & 127;
    const float mean = accum[0] * (1.0f / (float)BLC);
    const float var = accum[1] * (1.0f / (float)BLC) - mean * mean;
    const float zi = z[idx];
    z[idx] = upd_elem(zi, y[idx], mk[idx], eps[idx], l, c, ent, p1, p2, p3,
                      thr[0], thr[1], thr[2], thr[3], var, base_a, base_b,
                      h_lam);
}

// ---------------------------------------------------------------------------
extern "C" void kernel_launch(void* const* d_in, const int* in_sizes, int n_in,
                              void* d_out, int out_size, void* d_ws,
                              size_t ws_size, hipStream_t stream) {
    const float* y_obs = (const float*)d_in[0];
    const float* mask = (const float*)d_in[1];
    const float* z_init = (const float*)d_in[2];
    const float* W1 = (const float*)d_in[3];
    const float* b1 = (const float*)d_in[4];
    const float* W2 = (const float*)d_in[5];
    const float* b2 = (const float*)d_in[6];
    const float* tw = (const float*)d_in[7];
    float* z = (float*)d_out;
    float* ws = (float*)d_ws;

    // workspace layout (float offsets)
    float* eps = ws;                                 // 2097152
    float* ent = ws + 2097152;                       // 131072
    float* p1 = ws + 2228224;                        // 32768
    float* p2 = ws + 2260992;                        // 8192
    float* p3 = ws + 2269184;                        // 2048
    // zero block: ghist[16*1024] + ctr + rel + accum[8] + gprefix[4]
    unsigned* ghist = (unsigned*)(ws + 2271232);     // 16384 u32
    unsigned* ctr = (unsigned*)(ws + 2287616);       // 1
    unsigned* rel = (unsigned*)(ws + 2287617);       // 1
    float* accum = ws + 2287618;                     // 8 (2 per step)
    unsigned* gprefix = (unsigned*)(ws + 2287626);   // 4
    unsigned short* W1h = (unsigned short*)(ws + 2287632);  // 65536 u16 each
    unsigned short* W1m = (unsigned short*)(ws + 2320400);
    unsigned short* W1l = (unsigned short*)(ws + 2353168);
    unsigned short* W2h = (unsigned short*)(ws + 2385936);
    unsigned short* W2m = (unsigned short*)(ws + 2418704);
    unsigned short* W2l = (unsigned short*)(ws + 2451472);

    // diffusion schedule in fp32 (input-independent)
    float alpha_[1000], sigma_[1000], lam_[1000];
    {
        float ac = 1.0f;
        for (int i = 0; i < 1000; ++i) {
            const float beta = 1e-4f + (0.02f - 1e-4f) * ((float)i / 999.0f);
            ac = ac * (1.0f - beta);
            alpha_[i] = sqrtf(ac);
            sigma_[i] = sqrtf(1.0f - ac);
            lam_[i] = logf(alpha_[i]) - logf(sigma_[i]);
        }
    }
    float tf[4], hl[4], ba[4], bb[4];
    for (int si = 0; si < 4; ++si) {
        const int k = 999 - si * 250;
        const int kp = (k - 250 > 0) ? (k - 250) : 0;
        tf[si] = (float)k / 1000.0f;
        hl[si] = lam_[kp] - lam_[k];
        ba[si] = alpha_[kp] / alpha_[k];
        bb[si] = sigma_[kp] * (expf(hl[si]) - 1.0f);
    }

    hipMemcpyAsync(z, z_init, sizeof(float) * BLC, hipMemcpyDeviceToDevice,
                   stream);
    hipMemsetAsync(ghist, 0, (16384 + 2 + 8 + 4) * sizeof(unsigned), stream);
    wsplit_kernel<<<512, 256, 0, stream>>>(W1, W2, W1h, W1m, W1l, W2h, W2m,
                                           W2l);

    for (int si = 0; si < 4; ++si) {
        if (si == 0) {
            mlp_kernel<0><<<512, 512, 0, stream>>>(
                z, y_obs, mask, W1h, W1m, W1l, W2h, W2m, W2l, b1, tw, b2,
                tf[0], eps, ent, p1, p2, p3, gprefix, accum, accum, 0.f, 0.f,
                0.f);
        } else {
            mlp_kernel<1><<<512, 512, 0, stream>>>(
                z, y_obs, mask, W1h, W1m, W1l, W2h, W2m, W2l, b1, tw, b2,
                tf[si], eps, ent, p1, p2, p3, gprefix, accum + 2 * (si - 1),
                accum + 2 * si, ba[si - 1], bb[si - 1], hl[si - 1]);
        }
        select_kernel<<<85, 256, 0, stream>>>(ent, p1, p2, p3, ghist, ctr, rel,
                                              gprefix, si);
    }
    update_kernel<<<8192, 256, 0, stream>>>(z, y_obs, mask, eps, ent, p1, p2,
                                            p3, gprefix, accum + 6, ba[3],
                                            bb[3], hl[3]);
}

// Round 8
// 407.069 us; speedup vs baseline: 1.2420x; 1.2420x over previous
//
#include <hip/hip_runtime.h>
#include <math.h>
#include <stdint.h>

#define L_DIM 1024
#define C_DIM 128
#define H_DIM 512
#define B_DIM 16
#define LC (L_DIM * C_DIM)      // 131072
#define BLC (B_DIM * LC)        // 2097152

typedef __attribute__((ext_vector_type(8))) short short8;
typedef __attribute__((ext_vector_type(4))) float floatx4;

// ---------------- monotone float/bits -> ordered uint ----------------------
__device__ __forceinline__ unsigned fordbits(unsigned u) {
    return (u & 0x80000000u) ? ~u : (u | 0x80000000u);
}

// ---------------- truncation 3-way bf16 split: x = h + m + l + O(2^-24 x) --
__device__ __forceinline__ void split3(float x, unsigned& uh, unsigned& um,
                                       unsigned& ul) {
    uh = __float_as_uint(x);
    const float r1 = x - __uint_as_float(uh & 0xffff0000u);
    um = __float_as_uint(r1);
    const float r2 = r1 - __uint_as_float(um & 0xffff0000u);
    ul = __float_as_uint(r2);
}

__device__ __forceinline__ float gelu_fast(float x) {
    const float g = 0.7978845608028654f * (x + 0.044715f * x * x * x);
    const float e = __expf(2.0f * g);
    const float t = 1.0f - 2.0f / (e + 1.0f);
    return 0.5f * x * (1.0f + t);
}

// ---------------- W pre-split into MFMA B-frag layout (h/m/l bf16) ---------
__global__ __launch_bounds__(256) void wsplit_kernel(
    const float* __restrict__ W1, const float* __restrict__ W2,
    unsigned short* __restrict__ W1h, unsigned short* __restrict__ W1m,
    unsigned short* __restrict__ W1l, unsigned short* __restrict__ W2h,
    unsigned short* __restrict__ W2m, unsigned short* __restrict__ W2l) {
    const int t = blockIdx.x * 256 + threadIdx.x;  // < 131072
    unsigned uh, um, ul;
    if (t < 65536) {
        const int j = t & 7, lane = (t >> 3) & 63, nt = (t >> 9) & 31,
                  kt = (t >> 14) & 3;
        const int k = kt * 32 + (lane >> 4) * 8 + j;
        const int n = nt * 16 + (lane & 15);
        split3(W1[k * 512 + n], uh, um, ul);
        W1h[t] = (unsigned short)(uh >> 16);
        W1m[t] = (unsigned short)(um >> 16);
        W1l[t] = (unsigned short)(ul >> 16);
    } else {
        const int t2 = t - 65536;
        const int j = t2 & 7, lane = (t2 >> 3) & 63, nt = (t2 >> 9) & 7,
                  kt = (t2 >> 12) & 15;
        const int k = kt * 32 + (lane >> 4) * 8 + j;
        const int n = nt * 16 + (lane & 15);
        split3(W2[k * 128 + n], uh, um, ul);
        W2h[t2] = (unsigned short)(uh >> 16);
        W2m[t2] = (unsigned short)(um >> 16);
        W2l[t2] = (unsigned short)(ul >> 16);
    }
}

// 6-term bf16x3 MFMA accumulate (small terms first); error ~2^-24
#define MFMA6(AH, AM, AL, BH, BM, BL, ACC)                                    \
    ACC = __builtin_amdgcn_mfma_f32_16x16x32_bf16(AL, BH, ACC, 0, 0, 0);      \
    ACC = __builtin_amdgcn_mfma_f32_16x16x32_bf16(AM, BM, ACC, 0, 0, 0);      \
    ACC = __builtin_amdgcn_mfma_f32_16x16x32_bf16(AH, BL, ACC, 0, 0, 0);      \
    ACC = __builtin_amdgcn_mfma_f32_16x16x32_bf16(AM, BH, ACC, 0, 0, 0);      \
    ACC = __builtin_amdgcn_mfma_f32_16x16x32_bf16(AH, BM, ACC, 0, 0, 0);      \
    ACC = __builtin_amdgcn_mfma_f32_16x16x32_bf16(AH, BH, ACC, 0, 0, 0);

// XOR-swizzled LDS address for A-tiles: 32 rows x 128 cols of ushort,
// addr = row*128 + ((chunk ^ (row&15))<<3) + (col&7), chunk = col>>3.
// Staging writes, h-writes and frag ds_read_b128 are all conflict-free.
__device__ __forceinline__ int swz(int row, int col) {
    return row * 128 + ((((col >> 3) ^ (row & 15))) << 3) + (col & 7);
}

// ---------------- fused MLP (+ previous step's DPM update when UPD) --------
// Block: 512 thr (8 waves), M=32 rows (16 b x 2 l), grid 512 (2 blocks/CU).
// Phase 1 applies prev step's update via PRECOMPUTED per-pixel coeff maps
// (cA,cB,cG) -- pure streaming float4, no divergent dependent lookups (R7's
// fused upd_elem was latency-bound: 4-level scattered L2 chains, mlp 79us).
// GEMM1 computes all H into acc1[8]; 4 quarter-phases run GEMM2.
template <int UPD>
__global__ __launch_bounds__(512, 4) void mlp_kernel(
    float* __restrict__ z, const float* __restrict__ y,
    const float* __restrict__ mk,
    const unsigned short* __restrict__ W1h, const unsigned short* __restrict__ W1m,
    const unsigned short* __restrict__ W1l, const unsigned short* __restrict__ W2h,
    const unsigned short* __restrict__ W2m, const unsigned short* __restrict__ W2l,
    const float* __restrict__ b1, const float* __restrict__ tw,
    const float* __restrict__ b2, float t_feat,
    float* __restrict__ eps_buf, float* __restrict__ ent,
    const float* __restrict__ cA, const float* __restrict__ cB,
    const float* __restrict__ cG, float* __restrict__ accum) {
    __shared__ unsigned short zA[3][4096];  // swizzled [row<32][col<128]
    __shared__ unsigned short hA[3][4096];  // swizzled h quarter
    __shared__ float red1[8], red2[8];
    const int tid = threadIdx.x;
    const int w = tid >> 6, lane = tid & 63;
    const int quad = lane >> 4, m16 = lane & 15;
    const int l0 = blockIdx.x * 2;

    // ---- phase 1: (coeff-map update) + stats + stage split z into LDS ----
    float s1 = 0.f, s2 = 0.f;
#pragma unroll
    for (int e = 0; e < 2; ++e) {
        const int f = tid * 8 + e * 4;  // 0..4095
        const int r_ = f >> 7, cb = f & 127;
        const int b = r_ & 15, il = r_ >> 4, l = l0 + il;
        const size_t g = ((size_t)b * 1024 + l) * 128 + cb;
        float4 zv = *(const float4*)(z + g);
        const float4 yv = *(const float4*)(y + g);
        const float4 mv = *(const float4*)(mk + g);
        if (UPD) {
            const float4 ev = *(const float4*)(eps_buf + g);
            const int pix = l * 128 + cb;
            const float4 a4 = *(const float4*)(cA + pix);
            const float4 b4 = *(const float4*)(cB + pix);
            const float4 g4 = *(const float4*)(cG + pix);
            zv.x = a4.x * zv.x - b4.x * ev.x - g4.x * ((zv.x - yv.x) * mv.x);
            zv.y = a4.y * zv.y - b4.y * ev.y - g4.y * ((zv.y - yv.y) * mv.y);
            zv.z = a4.z * zv.z - b4.z * ev.z - g4.z * ((zv.z - yv.z) * mv.z);
            zv.w = a4.w * zv.w - b4.w * ev.w - g4.w * ((zv.w - yv.w) * mv.w);
            *(float4*)(z + g) = zv;
        }
        float oe;
        oe = (zv.x - yv.x) * mv.x; s1 += oe; s2 += oe * oe;
        oe = (zv.y - yv.y) * mv.y; s1 += oe; s2 += oe * oe;
        oe = (zv.z - yv.z) * mv.z; s1 += oe; s2 += oe * oe;
        oe = (zv.w - yv.w) * mv.w; s1 += oe; s2 += oe * oe;

        // swizzled staging (ushort4 = 8B per array; conflict-free)
        const int base = swz(r_, cb);
        const float xs[4] = {zv.x, zv.y, zv.z, zv.w};
        ushort4 vh, vm, vl;
        unsigned uh, um, ul;
        split3(xs[0], uh, um, ul); vh.x = uh >> 16; vm.x = um >> 16; vl.x = ul >> 16;
        split3(xs[1], uh, um, ul); vh.y = uh >> 16; vm.y = um >> 16; vl.y = ul >> 16;
        split3(xs[2], uh, um, ul); vh.z = uh >> 16; vm.z = um >> 16; vl.z = ul >> 16;
        split3(xs[3], uh, um, ul); vh.w = uh >> 16; vm.w = um >> 16; vl.w = ul >> 16;
        *(ushort4*)(&zA[0][base]) = vh;
        *(ushort4*)(&zA[1][base]) = vm;
        *(ushort4*)(&zA[2][base]) = vl;
    }
#pragma unroll
    for (int off = 32; off; off >>= 1) {
        s1 += __shfl_down(s1, off);
        s2 += __shfl_down(s2, off);
    }
    if (lane == 0) { red1[w] = s1; red2[w] = s2; }
    __syncthreads();  // staging + red complete
    if (tid == 0) {
        float a1 = 0.f, a2 = 0.f;
#pragma unroll
        for (int i = 0; i < 8; ++i) { a1 += red1[i]; a2 += red2[i]; }
        atomicAdd(&accum[0], a1);
        atomicAdd(&accum[1], a2);
    }

    // ---- GEMM1 (all H): acc1[q*2+il], wave's nt1 = q*8 + w ----
    floatx4 acc1[8];
#pragma unroll
    for (int i = 0; i < 8; ++i) acc1[i] = (floatx4){0.f, 0.f, 0.f, 0.f};

#pragma unroll
    for (int kt = 0; kt < 4; ++kt) {
        short8 Ah[2], Am[2], Al[2];
#pragma unroll
        for (int il = 0; il < 2; ++il) {
            const int fb = swz(il * 16 + m16, kt * 32 + quad * 8);
            Ah[il] = *(const short8*)(&zA[0][fb]);
            Am[il] = *(const short8*)(&zA[1][fb]);
            Al[il] = *(const short8*)(&zA[2][fb]);
        }
#pragma unroll
        for (int q = 0; q < 4; ++q) {
            const size_t off = ((size_t)(kt * 32 + q * 8 + w) * 64 + lane) * 8;
            const short8 bh = *(const short8*)(W1h + off);
            const short8 bm = *(const short8*)(W1m + off);
            const short8 bl = *(const short8*)(W1l + off);
#pragma unroll
            for (int il = 0; il < 2; ++il) {
                floatx4 a = acc1[q * 2 + il];
                MFMA6(Ah[il], Am[il], Al[il], bh, bm, bl, a);
                acc1[q * 2 + il] = a;
            }
        }
    }

    // ---- quarter phases: gelu+split h -> swizzled LDS, GEMM2 partial-K ----
    floatx4 acc2[2];
    acc2[0] = (floatx4){0.f, 0.f, 0.f, 0.f};
    acc2[1] = (floatx4){0.f, 0.f, 0.f, 0.f};

    for (int q = 0; q < 4; ++q) {
        __syncthreads();  // prior quarter's hA reads (or GEMM1) done
        {
            const int colg = q * 128 + w * 16 + m16;
            const float bb = b1[colg] + t_feat * tw[colg];
            const int kcol = w * 16 + m16;  // quarter-local k col
#pragma unroll
            for (int il = 0; il < 2; ++il) {
#pragma unroll
                for (int r = 0; r < 4; ++r) {
                    const float x = gelu_fast(acc1[q * 2 + il][r] + bb);
                    unsigned uh, um, ul;
                    split3(x, uh, um, ul);
                    const int idx = swz(il * 16 + quad * 4 + r, kcol);
                    hA[0][idx] = (unsigned short)(uh >> 16);
                    hA[1][idx] = (unsigned short)(um >> 16);
                    hA[2][idx] = (unsigned short)(ul >> 16);
                }
            }
        }
        __syncthreads();

#pragma unroll
        for (int ktl = 0; ktl < 4; ++ktl) {
            short8 Ah2[2], Am2[2], Al2[2];
#pragma unroll
            for (int il = 0; il < 2; ++il) {
                const int fb = swz(il * 16 + m16, ktl * 32 + quad * 8);
                Ah2[il] = *(const short8*)(&hA[0][fb]);
                Am2[il] = *(const short8*)(&hA[1][fb]);
                Al2[il] = *(const short8*)(&hA[2][fb]);
            }
            const size_t off =
                ((size_t)((q * 4 + ktl) * 8 + w) * 64 + lane) * 8;
            const short8 bh = *(const short8*)(W2h + off);
            const short8 bm = *(const short8*)(W2m + off);
            const short8 bl = *(const short8*)(W2l + off);
#pragma unroll
            for (int il = 0; il < 2; ++il) {
                floatx4 a = acc2[il];
                MFMA6(Ah2[il], Am2[il], Al2[il], bh, bm, bl, a);
                acc2[il] = a;
            }
        }
    }

    // ---- epilogue: +b2, write eps, ent = mean_b |eps| ----
    {
        const int col = w * 16 + m16;
        const float bb2 = b2[col];
#pragma unroll
        for (int il = 0; il < 2; ++il) {
            float pa = 0.f;
#pragma unroll
            for (int r = 0; r < 4; ++r) {
                const float e = acc2[il][r] + bb2;
                const int b = quad * 4 + r;
                eps_buf[((size_t)b * 1024 + l0 + il) * 128 + col] = e;
                pa += fabsf(e);
            }
            pa += __shfl_xor(pa, 16);
            pa += __shfl_xor(pa, 32);
            if (quad == 0) ent[(l0 + il) * 128 + col] = pa * (1.0f / 16.0f);
        }
    }
}

// ---------------- device-atomic grid barrier (85 co-resident blocks) -------
// Stale-state safe: if rel is already nonzero (rocprof replay), falls through.
__device__ __forceinline__ void grid_barrier(unsigned* c, unsigned* r) {
    __syncthreads();
    if (threadIdx.x == 0) {
        __threadfence();
        if (atomicAdd(c, 1u) + 1u == 85u) atomicExch(r, 1u);
        else
            while (atomicAdd(r, 0u) == 0u) __builtin_amdgcn_s_sleep(8);
    }
    __syncthreads();
}

// -------- fused select: pools + radix top-k + per-pixel update coeffs ------
// 85 blocks x 256 thr (co-resident). Cross-block data written within this
// dispatch is accessed via device atomics (XCD L2 non-coherence, G16).
// Tail computes cA/cB/cG per pixel so downstream update is streaming-only.
__global__ __launch_bounds__(256, 1) void select_kernel(
    const float* __restrict__ ent, float* __restrict__ p1,
    float* __restrict__ p2, float* __restrict__ p3,
    unsigned* __restrict__ ghist, unsigned* __restrict__ ctr,
    unsigned* __restrict__ rel, unsigned* __restrict__ gprefix,
    float* __restrict__ cA, float* __restrict__ cB, float* __restrict__ cG,
    const float* __restrict__ accum_si, float base_a, float base_b,
    float h_lam, int si) {
    const int bid = blockIdx.x, t = threadIdx.x;
    const int gid = bid * 256 + t;
    const int slot0 = si * 6;

    // ---- pools, direct from ent (same summation order as R6, ref-proven) --
    for (int i = gid; i < 32768; i += 21760) {  // w=2: 512x64
        const int r = i >> 6, c = i & 63;
        float s = 0.f;
#pragma unroll
        for (int ii = 0; ii < 2; ++ii)
#pragma unroll
            for (int jj = 0; jj < 2; ++jj)
                s += ent[((r * 2 + ii) << 7) + c * 2 + jj];
        atomicExch((unsigned*)&p1[i], __float_as_uint(s * 0.25f));
    }
    for (int i = gid; i < 8192; i += 21760) {  // w=4: 256x32
        const int r = i >> 5, c = i & 31;
        float s = 0.f;
#pragma unroll
        for (int ii = 0; ii < 4; ++ii)
#pragma unroll
            for (int jj = 0; jj < 4; ++jj)
                s += ent[((r * 4 + ii) << 7) + c * 4 + jj];
        atomicExch((unsigned*)&p2[i], __float_as_uint(s * 0.0625f));
    }
    for (int i = gid; i < 2048; i += 21760) {  // w=8: 128x16
        const int r = i >> 4, c = i & 15;
        float s = 0.f;
#pragma unroll
        for (int ii = 0; ii < 8; ++ii)
#pragma unroll
            for (int jj = 0; jj < 8; ++jj)
                s += ent[((r * 8 + ii) << 7) + c * 8 + jj];
        atomicExch((unsigned*)&p3[i], __float_as_uint(s * (1.0f / 64.0f)));
    }
    grid_barrier(&ctr[slot0], &rel[slot0]);

    // ---- radix select (per-block redundant scan keeps prefix local) ----
    const float* data;
    int scale, base;
    unsigned K;
    if (bid < 64) { scale = 0; data = ent; base = bid * 2048; K = 26214u; }
    else if (bid < 80) { scale = 1; data = p1; base = (bid - 64) * 2048; K = 6553u; }
    else if (bid < 84) { scale = 2; data = p2; base = (bid - 80) * 2048; K = 1638u; }
    else { scale = 3; data = p3; base = 0; K = 409u; }

    __shared__ unsigned hist[4][256];
    __shared__ unsigned sh[256];
    __shared__ unsigned sh_dig, sh_krem;
    const int wv = t >> 6;
    unsigned prefix = 0u, krem = K;

    for (int p = 0; p < 4; ++p) {
        const int shift = 24 - 8 * p;
        const unsigned hmask = p ? (0xFFFFFFFFu << (shift + 8)) : 0u;
#pragma unroll
        for (int i = t; i < 1024; i += 256) ((unsigned*)hist)[i] = 0u;
        __syncthreads();
#pragma unroll
        for (int i = t; i < 2048; i += 256) {
            const unsigned raw = atomicAdd((unsigned*)&data[base + i], 0u);
            const unsigned u = fordbits(raw);
            if ((u & hmask) == (prefix & hmask))
                atomicAdd(&hist[wv][(u >> shift) & 255u], 1u);
        }
        __syncthreads();
        const unsigned c = hist[0][t] + hist[1][t] + hist[2][t] + hist[3][t];
        unsigned* gh = &ghist[((si * 4 + p) * 4 + scale) * 256];
        if (c) atomicAdd(&gh[t], c);
        grid_barrier(&ctr[slot0 + 1 + p], &rel[slot0 + 1 + p]);
        sh[t] = atomicAdd(&gh[t], 0u);
        __syncthreads();
#pragma unroll
        for (int off = 1; off < 256; off <<= 1) {
            const unsigned v = (t + off < 256) ? sh[t + off] : 0u;
            __syncthreads();
            sh[t] += v;
            __syncthreads();
        }
        const unsigned suf = sh[t];
        const unsigned sufn = (t < 255) ? sh[t + 1] : 0u;
        if (suf >= krem && sufn < krem) {  // unique crossing
            sh_dig = (unsigned)t;
            sh_krem = krem - sufn;
        }
        __syncthreads();
        prefix |= (sh_dig << shift);
        krem = sh_krem;
        __syncthreads();
    }
    if (t == 0 && base == 0) atomicExch(&gprefix[scale], prefix);
    grid_barrier(&ctr[slot0 + 5], &rel[slot0 + 5]);

    // ---- coeff maps: per pixel, z_new = cA*z - cB*eps - cG*(z-y)*m ----
    const unsigned t0 = atomicAdd(&gprefix[0], 0u);
    const unsigned t1 = atomicAdd(&gprefix[1], 0u);
    const unsigned t2 = atomicAdd(&gprefix[2], 0u);
    const unsigned t3 = atomicAdd(&gprefix[3], 0u);
    const float mean = accum_si[0] * (1.0f / (float)BLC);
    const float var = accum_si[1] * (1.0f / (float)BLC) - mean * mean;
    const float vinv = 1.0f / (var + 1e-8f);

    for (int i = gid; i < LC; i += 21760) {
        const int l = i >> 7, c = i & 127;
        float ent_v = 0.f;
        bool sel = false;
        const float v0 = ent[i];
        if (fordbits(__float_as_uint(v0)) >= t0) { ent_v = v0; sel = true; }
        else {
            const float v1 = __uint_as_float(atomicAdd(
                (unsigned*)&p1[((l >> 1) << 6) + (c >> 1)], 0u));
            if (fordbits(__float_as_uint(v1)) >= t1) { ent_v = v1; sel = true; }
            else {
                const float v2 = __uint_as_float(atomicAdd(
                    (unsigned*)&p2[((l >> 2) << 5) + (c >> 2)], 0u));
                if (fordbits(__float_as_uint(v2)) >= t2) { ent_v = v2; sel = true; }
                else {
                    const float v3 = __uint_as_float(atomicAdd(
                        (unsigned*)&p3[((l >> 3) << 4) + (c >> 3)], 0u));
                    if (fordbits(__float_as_uint(v3)) >= t3) { ent_v = v3; sel = true; }
                }
            }
        }
        if (sel) {
            float corr;
            if (ent_v > 0.5f)
                corr = 1.0f + h_lam + h_lam * h_lam * (1.0f / 3.0f);
            else if (ent_v > 0.1f)
                corr = 1.0f + 0.5f * h_lam;
            else
                corr = 1.0f;
            cA[i] = base_a;
            cB[i] = base_b * corr;
            cG[i] = (2.0f * ent_v / (ent_v + 1.0f)) * vinv;
        } else {
            cA[i] = 1.0f;
            cB[i] = 0.f;
            cG[i] = 0.f;
        }
    }
}

// ---------------- standalone final update (coeff-map streaming) ------------
__global__ __launch_bounds__(256) void update_kernel(
    float* __restrict__ z, const float* __restrict__ y,
    const float* __restrict__ mk, const float* __restrict__ eps,
    const float* __restrict__ cA, const float* __restrict__ cB,
    const float* __restrict__ cG) {
    const int idx = blockIdx.x * 256 + threadIdx.x;  // < BLC
    const int p = idx & (LC - 1);
    const float zi = z[idx];
    z[idx] = cA[p] * zi - cB[p] * eps[idx] - cG[p] * ((zi - y[idx]) * mk[idx]);
}

// ---------------------------------------------------------------------------
extern "C" void kernel_launch(void* const* d_in, const int* in_sizes, int n_in,
                              void* d_out, int out_size, void* d_ws,
                              size_t ws_size, hipStream_t stream) {
    const float* y_obs = (const float*)d_in[0];
    const float* mask = (const float*)d_in[1];
    const float* z_init = (const float*)d_in[2];
    const float* W1 = (const float*)d_in[3];
    const float* b1 = (const float*)d_in[4];
    const float* W2 = (const float*)d_in[5];
    const float* b2 = (const float*)d_in[6];
    const float* tw = (const float*)d_in[7];
    float* z = (float*)d_out;
    float* ws = (float*)d_ws;

    // workspace layout (float offsets)
    float* eps = ws;                                 // 2097152
    float* ent = ws + 2097152;                       // 131072
    float* p1 = ws + 2228224;                        // 32768
    float* p2 = ws + 2260992;                        // 8192
    float* p3 = ws + 2269184;                        // 2048
    float* cA = ws + 2271232;                        // 131072
    float* cB = ws + 2402304;                        // 131072
    float* cG = ws + 2533376;                        // 131072
    // zero block: ghist[16*1024] + ctr[24] + rel[24] + accum[8] + gprefix[4]
    unsigned* ghist = (unsigned*)(ws + 2664448);     // 16384 u32
    unsigned* ctr = (unsigned*)(ws + 2680832);       // 24
    unsigned* rel = (unsigned*)(ws + 2680856);       // 24
    float* accum = ws + 2680880;                     // 8 (2 per step)
    unsigned* gprefix = (unsigned*)(ws + 2680888);   // 4
    unsigned short* W1h = (unsigned short*)(ws + 2680896);  // 65536 u16 each
    unsigned short* W1m = (unsigned short*)(ws + 2713664);
    unsigned short* W1l = (unsigned short*)(ws + 2746432);
    unsigned short* W2h = (unsigned short*)(ws + 2779200);
    unsigned short* W2m = (unsigned short*)(ws + 2811968);
    unsigned short* W2l = (unsigned short*)(ws + 2844736);

    // diffusion schedule in fp32 (input-independent)
    float alpha_[1000], sigma_[1000], lam_[1000];
    {
        float ac = 1.0f;
        for (int i = 0; i < 1000; ++i) {
            const float beta = 1e-4f + (0.02f - 1e-4f) * ((float)i / 999.0f);
            ac = ac * (1.0f - beta);
            alpha_[i] = sqrtf(ac);
            sigma_[i] = sqrtf(1.0f - ac);
            lam_[i] = logf(alpha_[i]) - logf(sigma_[i]);
        }
    }
    float tf[4], hl[4], ba[4], bb[4];
    for (int si = 0; si < 4; ++si) {
        const int k = 999 - si * 250;
        const int kp = (k - 250 > 0) ? (k - 250) : 0;
        tf[si] = (float)k / 1000.0f;
        hl[si] = lam_[kp] - lam_[k];
        ba[si] = alpha_[kp] / alpha_[k];
        bb[si] = sigma_[kp] * (expf(hl[si]) - 1.0f);
    }

    hipMemcpyAsync(z, z_init, sizeof(float) * BLC, hipMemcpyDeviceToDevice,
                   stream);
    hipMemsetAsync(ghist, 0, (16384 + 24 + 24 + 8 + 4) * sizeof(unsigned),
                   stream);
    wsplit_kernel<<<512, 256, 0, stream>>>(W1, W2, W1h, W1m, W1l, W2h, W2m,
                                           W2l);

    for (int si = 0; si < 4; ++si) {
        if (si == 0) {
            mlp_kernel<0><<<512, 512, 0, stream>>>(
                z, y_obs, mask, W1h, W1m, W1l, W2h, W2m, W2l, b1, tw, b2,
                tf[0], eps, ent, cA, cB, cG, accum);
        } else {
            mlp_kernel<1><<<512, 512, 0, stream>>>(
                z, y_obs, mask, W1h, W1m, W1l, W2h, W2m, W2l, b1, tw, b2,
                tf[si], eps, ent, cA, cB, cG, accum + 2 * si);
        }
        select_kernel<<<85, 256, 0, stream>>>(
            ent, p1, p2, p3, ghist, ctr, rel, gprefix, cA, cB, cG,
            accum + 2 * si, ba[si], bb[si], hl[si], si);
    }
    update_kernel<<<8192, 256, 0, stream>>>(z, y_obs, mask, eps, cA, cB, cG);
}